// Round 7
// baseline (167.180 us; speedup 1.0000x reference)
//
#include <hip/hip_runtime.h>

#define B_   16
#define C_   64
#define N_   2048
#define K_   20
#define O_   64
#define EPS_ 1e-5f

#define NT   32            // points per block
#define RP   64            // padded r per c-chunk (60 real + 4 zero)
#define CT   (C_*3)        // 192

typedef float  f32x4 __attribute__((ext_vector_type(4)));
typedef short  s16x8 __attribute__((ext_vector_type(8)));

__device__ __forceinline__ unsigned short f2bf(float x) {
    union { float f; unsigned int u; } v; v.f = x;
    unsigned int r = (v.u + 0x7fffu + ((v.u >> 16) & 1u)) >> 16;
    return (unsigned short)r;
}

// global_load_lds: 16B per lane, LDS dest = uniform base + lane*16
#define GLD_LDS16(gsrc, ldst) \
    __builtin_amdgcn_global_load_lds( \
        (const __attribute__((address_space(1))) unsigned int*)(gsrc), \
        (__attribute__((address_space(3)))       unsigned int*)(ldst), 16, 0, 0)

// ---------------------------------------------------------------------------
// Prep: W2fb stored PRE-SWIZZLED so a linear global_load_lds copy lands each
// 16B slot at LDS byte o*128 + ((kb^(o&7))<<4)  (kb = r>>3, j = r&7).
//   value = W2[o, c*3+t, k] * gamma[o]/sqrt(var[o]+eps),  r = t*20+k, pad r>=60
// ---------------------------------------------------------------------------
__global__ void prep_kernel(const float* __restrict__ W2,
                            const float* __restrict__ b2,
                            const float* __restrict__ gamma,
                            const float* __restrict__ beta,
                            const float* __restrict__ run_mean,
                            const float* __restrict__ run_var,
                            unsigned short* __restrict__ W2fb,
                            float* __restrict__ bias2) {
    int e = blockIdx.x * blockDim.x + threadIdx.x;
    const int total = C_ * O_ * RP;      // 262144
    if (e < total) {
        int r = e & 63;
        int o = (e >> 6) & 63;
        int c = e >> 12;
        float v = 0.f;
        if (r < 60) {
            int t = r / K_, k = r % K_;
            float inv = gamma[o] * rsqrtf(run_var[o] + EPS_);
            v = W2[(o * CT + (c * 3 + t)) * K_ + k] * inv;
        }
        int kb = r >> 3, j = r & 7;
        int slot = (o << 3) | (kb ^ (o & 7));          // swizzled slot in chunk
        W2fb[((size_t)c << 12) | (slot << 3) | j] = f2bf(v);
    } else if (e < total + O_) {
        int o = e - total;
        float inv = gamma[o] * rsqrtf(run_var[o] + EPS_);
        bias2[o] = (b2[o] - run_mean[o]) * inv + beta[o];
    }
}

// ---------------------------------------------------------------------------
// Main: block = (b, 32-pt tile), 128 threads (2 waves).
// out[64o][32pt] = sum_r W[r][o]*P[r][pt];  A = W^T LDS [o][64r] bf16 swz
// (loaded by global_load_lds from pre-swizzled W2fb, double-buffered);
// B = P LDS [pt][64r] bf16 swz; taylor kept in 15 registers per thread.
// ---------------------------------------------------------------------------
__global__ __launch_bounds__(128) void spider_mfma(
    const float* __restrict__ feat,
    const int*   __restrict__ idx,
    const float* __restrict__ gpc,
    const float* __restrict__ W1,
    const float* __restrict__ b1,
    const unsigned short* __restrict__ W2fb,
    const float* __restrict__ bias2,
    float* __restrict__ out)
{
    __shared__ __align__(16) unsigned short s_Wd[2][O_ * RP]; // 2 x 8 KB
    __shared__ __align__(16) unsigned short s_P[NT * RP];     // 4 KB [pt][r] swz
    __shared__ __align__(16) float          s_w1[64];

    const int tid = threadIdx.x;
    const int b   = blockIdx.y;
    const int n0  = blockIdx.x * NT;
    const int pt  = tid & 31;
    const int grp = tid >> 5;          // 0..3
    const int k0  = grp * 5;
    const int w   = tid >> 6;          // wave id 0..1
    const int l   = tid & 63;          // lane

    // stage W1/b1; zero the P pad rows (r=60..63 -> slot 7, bytes 8..15)
    if (tid < 57)      s_w1[tid] = W1[tid];
    else if (tid < 60) s_w1[tid] = b1[tid - 57];
    if (tid < NT) {
        int addr = tid * 128 + ((7 ^ (tid & 7)) << 4) + 8;
        *(unsigned long long*)((char*)s_P + addr) = 0ull;
    }

    // ---- prefetch W chunk c=0 into buffer 0 (linear DMA, src pre-swizzled)
    {
        const char* wsrc = (const char*)W2fb;
        #pragma unroll
        for (int q = 0; q < 4; ++q) {
            int chunk = (w * 4 + q) * 1024;
            GLD_LDS16(wsrc + chunk + l * 16, (char*)s_Wd[0] + chunk);
        }
    }
    __syncthreads();   // s_w1 ready (also drains the prefetch)

    // ---- taylor terms -> 15 registers (this thread's pt, its 5 k's, 3 t's)
    float tayr[15];
    {
        const float* pcb = gpc + ((size_t)b * 3 * N_ + (n0 + pt)) * K_;
        #pragma unroll
        for (int i = 0; i < 5; ++i) {
            int k = k0 + i;
            float X = pcb[k];
            float Y = pcb[(size_t)N_ * K_ + k];
            float Z = pcb[(size_t)2 * N_ * K_ + k];
            float XX = X * X, YY = Y * Y, ZZ = Z * Z;
            float XY = X * Y, XZ = X * Z, YZ = Y * Z;
            float tm[19] = {X, Y, Z, XX, YY, ZZ,
                            XX * X, YY * Y, ZZ * Z,
                            XY, XZ, YZ,
                            X * XY, X * XZ, Y * YZ,
                            Y * XY, Z * XZ, Z * YZ, XY * Z};
            #pragma unroll
            for (int t = 0; t < 3; ++t) {
                float a = s_w1[57 + t];
                #pragma unroll
                for (int j = 0; j < 19; ++j) a += s_w1[t * 19 + j] * tm[j];
                tayr[t * 5 + i] = a;
            }
        }
    }

    // idx values held in registers for the whole c-loop
    int iv[5];
    {
        const int* ig = idx + ((size_t)b * N_ + n0 + pt) * K_ + k0;
        #pragma unroll
        for (int i = 0; i < 5; ++i) iv[i] = ig[i];
    }

    f32x4 acc[2][2];
    #pragma unroll
    for (int mt = 0; mt < 2; ++mt)
        #pragma unroll
        for (int nt = 0; nt < 2; ++nt)
            acc[mt][nt] = (f32x4){0.f, 0.f, 0.f, 0.f};

    const float* featb = feat + (size_t)b * C_ * N_;

    for (int c = 0; c < C_; ++c) {
        const int cur = c & 1;

        // ---- prefetch W chunk c+1 into other buffer (overlaps gather phase)
        if (c < C_ - 1) {
            const char* wsrc = (const char*)(W2fb + ((size_t)(c + 1) << 12));
            #pragma unroll
            for (int q = 0; q < 4; ++q) {
                int chunk = (w * 4 + q) * 1024;
                GLD_LDS16(wsrc + chunk + l * 16, (char*)s_Wd[cur ^ 1] + chunk);
            }
        }

        // ---- gather (regs) + form P (bf16, swizzled b16 writes) ----
        const float* fr = featb + (size_t)c * N_;
        #pragma unroll
        for (int i = 0; i < 5; ++i) {
            int k = k0 + i;
            float g = fr[iv[i]];
            #pragma unroll
            for (int t = 0; t < 3; ++t) {
                float p = g * tayr[t * 5 + i];
                int byte = (t * K_ + k) * 2;
                int addr = pt * 128 + (((byte >> 4) ^ (pt & 7)) << 4) + (byte & 15);
                *(unsigned short*)((char*)s_P + addr) = f2bf(p);
            }
        }
        __syncthreads();

        // ---- MFMA: wave w covers o in [w*32, w*32+32), all 32 pts ----
        const unsigned short* sW = s_Wd[cur];
        #pragma unroll
        for (int ks = 0; ks < 2; ++ks) {
            int kb8 = ks * 4 + (l >> 4);
            int o0 = w * 32 + (l & 15);
            int o1 = o0 + 16;
            int p0 = (l & 15);
            int p1 = p0 + 16;
            s16x8 a0 = *(const s16x8*)((const char*)sW + o0 * 128 + ((kb8 ^ (o0 & 7)) << 4));
            s16x8 a1 = *(const s16x8*)((const char*)sW + o1 * 128 + ((kb8 ^ (o1 & 7)) << 4));
            s16x8 b0 = *(const s16x8*)((char*)s_P + p0 * 128 + ((kb8 ^ (p0 & 7)) << 4));
            s16x8 b1 = *(const s16x8*)((char*)s_P + p1 * 128 + ((kb8 ^ (p1 & 7)) << 4));
            acc[0][0] = __builtin_amdgcn_mfma_f32_16x16x32_bf16(a0, b0, acc[0][0], 0, 0, 0);
            acc[0][1] = __builtin_amdgcn_mfma_f32_16x16x32_bf16(a0, b1, acc[0][1], 0, 0, 0);
            acc[1][0] = __builtin_amdgcn_mfma_f32_16x16x32_bf16(a1, b0, acc[1][0], 0, 0, 0);
            acc[1][1] = __builtin_amdgcn_mfma_f32_16x16x32_bf16(a1, b1, acc[1][1], 0, 0, 0);
        }
        __syncthreads();   // P reusable + prefetched W resident (vmcnt drained)
    }

    // ---- epilogue: bias + relu; D row=(l>>4)*4+reg (=o), col=l&15 (=pt) ----
    #pragma unroll
    for (int mt = 0; mt < 2; ++mt) {
        #pragma unroll
        for (int nt = 0; nt < 2; ++nt) {
            #pragma unroll
            for (int r = 0; r < 4; ++r) {
                int o = w * 32 + mt * 16 + (l >> 4) * 4 + r;
                int n = n0 + nt * 16 + (l & 15);
                float v = acc[mt][nt][r] + bias2[o];
                out[((size_t)b * O_ + o) * N_ + n] = fmaxf(v, 0.f);
            }
        }
    }
}

extern "C" void kernel_launch(void* const* d_in, const int* in_sizes, int n_in,
                              void* d_out, int out_size, void* d_ws, size_t ws_size,
                              hipStream_t stream) {
    const float* feat     = (const float*)d_in[0];
    const int*   idx      = (const int*)  d_in[1];
    const float* gpc      = (const float*)d_in[2];
    const float* W1       = (const float*)d_in[3];
    const float* b1       = (const float*)d_in[4];
    const float* W2       = (const float*)d_in[5];
    const float* b2       = (const float*)d_in[6];
    const float* gamma    = (const float*)d_in[7];
    const float* beta     = (const float*)d_in[8];
    const float* run_mean = (const float*)d_in[9];
    const float* run_var  = (const float*)d_in[10];
    float* out = (float*)d_out;

    unsigned short* W2fb = (unsigned short*)d_ws;                 // 512 KB
    float* bias2 = (float*)((char*)d_ws + (size_t)C_ * O_ * RP * 2);

    const int prep_total = C_ * O_ * RP + O_;
    prep_kernel<<<(prep_total + 255) / 256, 256, 0, stream>>>(
        W2, b2, gamma, beta, run_mean, run_var, W2fb, bias2);

    dim3 grid(N_ / NT, B_);
    spider_mfma<<<grid, 128, 0, stream>>>(
        feat, idx, gpc, W1, b1, W2fb, bias2, out);
}

// Round 8
// 145.085 us; speedup vs baseline: 1.1523x; 1.1523x over previous
//
#include <hip/hip_runtime.h>

#define B_   16
#define C_   64
#define N_   2048
#define K_   20
#define O_   64
#define EPS_ 1e-5f

#define NT   32            // points per block (one wave per block)
#define CT   (C_*3)        // 192

typedef float f32x4 __attribute__((ext_vector_type(4)));
typedef short s16x8 __attribute__((ext_vector_type(8)));

__device__ __forceinline__ unsigned short f2bf(float x) {
    union { float f; unsigned int u; } v; v.f = x;
    return (unsigned short)((v.u + 0x7fffu + ((v.u >> 16) & 1u)) >> 16);
}
__device__ __forceinline__ unsigned int pack2bf(float a, float b) {
    return (unsigned int)f2bf(a) | ((unsigned int)f2bf(b) << 16);
}

// ---------------------------------------------------------------------------
// Prep: W2fb in MFMA A-FRAGMENT order. Fragment (c, ot, ks), lane l, elem j:
//   o = ot*16 + (l&15),  r = ks*32 + (l>>4)*8 + j   (r = t*20+k, pad r>=60)
//   flat short index e = ((c*8 + ot*2+ks)*64 + l)*8 + j
//   value = W2[o, c*3+t, k] * gamma[o]/sqrt(var[o]+eps)
// ---------------------------------------------------------------------------
__global__ void prep_kernel(const float* __restrict__ W2,
                            const float* __restrict__ b2,
                            const float* __restrict__ gamma,
                            const float* __restrict__ beta,
                            const float* __restrict__ run_mean,
                            const float* __restrict__ run_var,
                            unsigned short* __restrict__ W2fb,
                            float* __restrict__ bias2) {
    int e = blockIdx.x * blockDim.x + threadIdx.x;
    const int total = C_ * 8 * 64 * 8;     // 262144
    if (e < total) {
        int j  = e & 7;
        int l  = (e >> 3) & 63;
        int f  = (e >> 9) & 7;
        int c  = e >> 12;
        int ot = f >> 1, ks = f & 1;
        int o  = ot * 16 + (l & 15);
        int r  = ks * 32 + ((l >> 4) << 3) + j;
        float v = 0.f;
        if (r < 60) {
            int t = r / K_, k = r % K_;
            float inv = gamma[o] * rsqrtf(run_var[o] + EPS_);
            v = W2[(o * CT + (c * 3 + t)) * K_ + k] * inv;
        }
        W2fb[e] = f2bf(v);
    } else if (e < total + O_) {
        int o = e - total;
        float inv = gamma[o] * rsqrtf(run_var[o] + EPS_);
        bias2[o] = (b2[o] - run_mean[o]) * inv + beta[o];
    }
}

// ---------------------------------------------------------------------------
// Main: ONE WAVE per block, 32 pts, all 64 o. ZERO barriers.
// W fragments: registers, coalesced dwordx4 from fragment-ordered W2fb (L2).
// P: LDS double-buffer [pt][64r] bf16, XOR swizzle byte^=((pt&7)<<4).
// Pipeline (unroll 2): issue W(c+2)/g(c+2) -> MFMA(c) -> write P(c+1).
// ---------------------------------------------------------------------------
__global__ __launch_bounds__(64) void spider_mfma(
    const float* __restrict__ feat,
    const int*   __restrict__ idx,
    const float* __restrict__ gpc,
    const float* __restrict__ W1,
    const float* __restrict__ b1,
    const unsigned short* __restrict__ W2fb,
    const float* __restrict__ bias2,
    float* __restrict__ out)
{
    __shared__ __align__(16) char sP[2][NT * 128];   // 2 x 4 KB

    const int tid = threadIdx.x;      // == lane (1 wave)
    const int b   = blockIdx.y;
    const int n0  = blockIdx.x * NT;
    const int pt  = tid & 31;
    const int grp = tid >> 5;         // 0..1 -> k-range grp*10..grp*10+9
    const int l   = tid;

    // zero the pad rows r=60..63 (slot 7, bytes 8..15) in both buffers
    *(unsigned long long*)(sP[tid >> 5] + (tid & 31) * 128 +
                           ((7 ^ (tid & 7)) << 4) + 8) = 0ull;

    // ---- taylor terms (30 regs) + idx (10 regs) for this thread ----
    float tayr[30];
    int   iv[10];
    {
        const int k0 = grp * 10;
        const float* pcb = gpc + ((size_t)b * 3 * N_ + (n0 + pt)) * K_ + k0;
        const int*   ig  = idx + ((size_t)b * N_ + (n0 + pt)) * K_ + k0;
        #pragma unroll
        for (int q = 0; q < 10; ++q) {
            iv[q] = ig[q];
            float X = pcb[q];
            float Y = pcb[N_ * K_ + q];
            float Z = pcb[2 * N_ * K_ + q];
            float XX = X * X, YY = Y * Y, ZZ = Z * Z;
            float XY = X * Y, XZ = X * Z, YZ = Y * Z;
            float tm[19] = {X, Y, Z, XX, YY, ZZ,
                            XX * X, YY * Y, ZZ * Z,
                            XY, XZ, YZ,
                            X * XY, X * XZ, Y * YZ,
                            Y * XY, Z * XZ, Z * YZ, XY * Z};
            #pragma unroll
            for (int t = 0; t < 3; ++t) {
                float a = b1[t];
                #pragma unroll
                for (int j = 0; j < 19; ++j) a += W1[t * 19 + j] * tm[j];
                tayr[t * 10 + q] = a;
            }
        }
    }

    const s16x8* Wfrag = (const s16x8*)W2fb;            // 512 frags per c
    const float* featb = feat + (size_t)b * C_ * N_;

    s16x8 wA[8], wB[8];
    float gA[10], gB[10];
    f32x4 acc[4][2];
    #pragma unroll
    for (int ot = 0; ot < 4; ++ot)
        #pragma unroll
        for (int p = 0; p < 2; ++p) acc[ot][p] = (f32x4){0.f, 0.f, 0.f, 0.f};

    auto issueW = [&](s16x8 (&w)[8], int cc) {
        const s16x8* p = Wfrag + (size_t)cc * 512 + l;
        #pragma unroll
        for (int f = 0; f < 8; ++f) w[f] = p[f * 64];
    };
    auto issueG = [&](float (&g)[10], int cc) {
        const float* fr = featb + (size_t)cc * N_;
        #pragma unroll
        for (int q = 0; q < 10; ++q) g[q] = fr[iv[q]];
    };
    auto writeP = [&](int buf, float (&g)[10]) {
        char* base = sP[buf] + pt * 128;
        #pragma unroll
        for (int t = 0; t < 3; ++t) {
            #pragma unroll
            for (int i = 0; i < 5; ++i) {
                int byte = t * 40 + grp * 20 + i * 4;
                unsigned int v = pack2bf(g[2 * i]     * tayr[t * 10 + 2 * i],
                                         g[2 * i + 1] * tayr[t * 10 + 2 * i + 1]);
                *(unsigned int*)(base + ((((byte >> 4) ^ (pt & 7))) << 4) + (byte & 15)) = v;
            }
        }
    };
    auto mfmaC = [&](s16x8 (&w)[8], int buf) {
        #pragma unroll
        for (int ks = 0; ks < 2; ++ks) {
            int kb8 = ks * 4 + (l >> 4);
            #pragma unroll
            for (int pti = 0; pti < 2; ++pti) {
                int p = pti * 16 + (l & 15);
                s16x8 bf = *(const s16x8*)(sP[buf] + p * 128 + ((kb8 ^ (p & 7)) << 4));
                #pragma unroll
                for (int ot = 0; ot < 4; ++ot)
                    acc[ot][pti] = __builtin_amdgcn_mfma_f32_16x16x32_bf16(
                        w[ot * 2 + ks], bf, acc[ot][pti], 0, 0, 0);
            }
        }
    };

    // ---- prologue: fill stage-0/1 ----
    issueG(gA, 0); issueW(wA, 0);
    writeP(0, gA);                       // P(0)
    issueG(gB, 1); issueW(wB, 1);

    // ---- main loop: 32 pairs, no barriers ----
    for (int c = 0; c < C_; c += 2) {
        mfmaC(wA, 0);                    // compute c   (W regs + Pbuf0)
        writeP(1, gB);                   // form P(c+1) (consumes g issued 1 iter ago)
        int c2 = (c + 2 < C_) ? c + 2 : C_ - 1;
        issueG(gA, c2); issueW(wA, c2);
        mfmaC(wB, 1);                    // compute c+1
        writeP(0, gA);                   // form P(c+2)
        int c3 = (c + 3 < C_) ? c + 3 : C_ - 1;
        issueG(gB, c3); issueW(wB, c3);
    }

    // ---- epilogue: bias + relu; D row=(l>>4)*4+reg (=o_local), col=l&15 ----
    #pragma unroll
    for (int ot = 0; ot < 4; ++ot) {
        f32x4 bv = *(const f32x4*)&bias2[ot * 16 + (l >> 4) * 4];
        #pragma unroll
        for (int pti = 0; pti < 2; ++pti) {
            #pragma unroll
            for (int r = 0; r < 4; ++r) {
                int o = ot * 16 + (l >> 4) * 4 + r;
                int n = n0 + pti * 16 + (l & 15);
                float v = acc[ot][pti][r] + bv[r];
                out[((size_t)b * O_ + o) * N_ + n] = fmaxf(v, 0.f);
            }
        }
    }
}

extern "C" void kernel_launch(void* const* d_in, const int* in_sizes, int n_in,
                              void* d_out, int out_size, void* d_ws, size_t ws_size,
                              hipStream_t stream) {
    const float* feat     = (const float*)d_in[0];
    const int*   idx      = (const int*)  d_in[1];
    const float* gpc      = (const float*)d_in[2];
    const float* W1       = (const float*)d_in[3];
    const float* b1       = (const float*)d_in[4];
    const float* W2       = (const float*)d_in[5];
    const float* b2       = (const float*)d_in[6];
    const float* gamma    = (const float*)d_in[7];
    const float* beta     = (const float*)d_in[8];
    const float* run_mean = (const float*)d_in[9];
    const float* run_var  = (const float*)d_in[10];
    float* out = (float*)d_out;

    unsigned short* W2fb = (unsigned short*)d_ws;                 // 512 KB
    float* bias2 = (float*)((char*)d_ws + (size_t)C_ * 8 * 64 * 8 * 2);

    const int prep_total = C_ * 8 * 64 * 8 + O_;
    prep_kernel<<<(prep_total + 255) / 256, 256, 0, stream>>>(
        W2, b2, gamma, beta, run_mean, run_var, W2fb, bias2);

    dim3 grid(N_ / NT, B_);
    spider_mfma<<<grid, 64, 0, stream>>>(
        feat, idx, gpc, W1, b1, W2fb, bias2, out);
}